// Round 3
// baseline (867.526 us; speedup 1.0000x reference)
//
#include <hip/hip_runtime.h>
#include <hip/hip_bf16.h>

typedef short bf16x8 __attribute__((ext_vector_type(8)));
typedef float f32x4 __attribute__((ext_vector_type(4)));

#define NH_ 12
#define DIM_ 384

static __device__ __forceinline__ float bf2f_us(ushort u) {
    __hip_bfloat16 h; __builtin_memcpy(&h, &u, 2);
    return __bfloat162float(h);
}
static __device__ __forceinline__ ushort f2us(float f) {
    __hip_bfloat16 h = __float2bfloat16(f);
    ushort u; __builtin_memcpy(&u, &h, 2);
    return u;
}

// async global->LDS, 16B per lane; LDS dest = base + lane*16 (wave-uniform base)
static __device__ __forceinline__ void gload_lds16(const void* g, void* l) {
    __builtin_amdgcn_global_load_lds(
        (const __attribute__((address_space(1))) unsigned int*)g,
        (__attribute__((address_space(3))) unsigned int*)l, 16, 0, 0);
}

static __device__ __forceinline__ int regioncnt(int t, int wr, int wc) {
    int rr = (wr == 7) ? (((t >> 3) < 4) ? 1 : 2) : 0;
    int cc = (wc == 7) ? (((t & 7) < 4) ? 1 : 2) : 0;
    return rr * 3 + cc;
}

// ---------------- convert f32 weights/biases/table -> bf16 in ws ----------------
// dst layout (ushort elements): wq[147456] wk wv wo | bq[384] bk bv bo | table[2700]
__global__ __launch_bounds__(256) void convert_kernel(
    const float* wq, const float* wk, const float* wv, const float* wo,
    const float* bq, const float* bk, const float* bv, const float* bo,
    const float* bt, ushort* __restrict__ dst)
{
    const int N = 594060;
    for (int i = blockIdx.x * 256 + threadIdx.x; i < N; i += gridDim.x * 256) {
        const float* src; int off;
        if (i < 589824) {
            int wsel = i / 147456; off = i - wsel * 147456;
            src = (wsel == 0) ? wq : (wsel == 1) ? wk : (wsel == 2) ? wv : wo;
        } else if (i < 591360) {
            int bsel = (i - 589824) / 384; off = (i - 589824) - bsel * 384;
            src = (bsel == 0) ? bq : (bsel == 1) ? bk : (bsel == 2) ? bv : bo;
        } else {
            off = i - 591360; src = bt;
        }
        dst[i] = f2us(src[off]);
    }
}

// ---------------- pre-masked bias in C-fragment layout ----------------
// biasv[v][h][tno=rt*4+ct][lane][r] (float4 per lane): v = (wr==7)*2 + (wc==7).
// attn reads one coalesced float4 per (rt,ct) per lane.
__global__ __launch_bounds__(256) void bias_kernel(
    const ushort* __restrict__ tablec, float* __restrict__ biasv)
{
    const int vh = blockIdx.x;                 // 0..47 = v*NH_ + h
    const int v = vh / NH_, h = vh - v * NH_;
    const int wr = (v & 2) ? 7 : 0, wc = (v & 1) ? 7 : 0;
    const int tid = threadIdx.x, lane = tid & 63;
    #pragma unroll
    for (int i = 0; i < 4; ++i) {
        const int tno = (tid >> 6) + 4 * i;    // 0..15
        const int rt = tno >> 2, ct = tno & 3;
        const int jj = ct * 16 + (lane & 15);
        const int cntj = regioncnt(jj, wr, wc);
        float4 o;
        float vals[4];
        #pragma unroll
        for (int r = 0; r < 4; ++r) {
            const int ii = rt * 16 + (lane >> 4) * 4 + r;
            const int idx = ((ii >> 3) - (jj >> 3) + 7) * 15 + ((ii & 7) - (jj & 7) + 7);
            float val = bf2f_us(tablec[idx * NH_ + h]);
            if (regioncnt(ii, wr, wc) != cntj) val -= 100.f;
            vals[r] = val;
        }
        o.x = vals[0]; o.y = vals[1]; o.z = vals[2]; o.w = vals[3];
        reinterpret_cast<float4*>(biasv)[((size_t)vh * 16 + tno) * 64 + lane] = o;
    }
}

// ---------------- QKV projection as 128x128x(BK=32) GEMM ----------------
// LDS slot order = MFMA lane order: subtile rb (16 rows) at [rb*1024,+1024) bytes,
// slot s = kchunk*16 + row  =>  fragment read is base + lane*16 (contiguous, 0-conflict).
__global__ __launch_bounds__(256, 4) void qkv_gemm(
    const float* __restrict__ x, const ushort* __restrict__ wb,
    ushort* __restrict__ qws, ushort* __restrict__ kws, ushort* __restrict__ vws,
    int wbase, int nmb)
{
    __shared__ __align__(16) ushort As[2][4096];
    __shared__ __align__(16) ushort Bs[2][4096];
    const int nwg = nmb * 9;
    const int orig = blockIdx.x;
    const int wgid = (orig & 7) * (nwg >> 3) + (orig >> 3);
    const int mb = wgid / 9, nt = wgid - mb * 9;
    const int wsel = nt / 3, ntm = nt - wsel * 3;
    const int n0 = nt * 128;
    const int tid = threadIdx.x, lane = tid & 63, wv = tid >> 6;
    const int col16 = lane & 15, quad = lane >> 4;
    const int wm = wv >> 1, wn = wv & 1;

    // A stage: thread t writes 8B (4 bf16) at byte it*2048 + t*8 ->
    // slot g = it*128 + t/2: rb = it*2+(t>>7), row16 = (t>>1)&15, kchunk = (t>>5)&3, half = t&1
    const int kofA = ((tid >> 5) & 3) * 8 + (tid & 1) * 4;
    const float* arow[4];
    #pragma unroll
    for (int it = 0; it < 4; ++it) {
        const int row = (it * 2 + (tid >> 7)) * 16 + ((tid >> 1) & 15);  // 0..127
        const int wglob = wbase + mb * 2 + (row >> 6);
        const int token = row & 63;
        const int b = wglob >> 6, widx = wglob & 63, wr = widx >> 3, wc = widx & 7;
        const int orr = (wr * 8 + (token >> 3) + 4) & 63;
        const int occ = (wc * 8 + (token & 7) + 4) & 63;
        arow[it] = x + (((size_t)b * 64 + orr) * 64 + occ) * DIM_ + kofA;
    }

    // B stage via global_load_lds (dest = base + lane*16): lane l supplies
    // slot l of block blk -> row = blk*16 + (l&15), kchunk = l>>4.
    const ushort* bsrc = wb + (size_t)n0 * DIM_;
    const int brow_l = lane & 15, bkof = (lane >> 4) * 8;

    f32x4 acc[4][4];
    #pragma unroll
    for (int i2 = 0; i2 < 4; ++i2)
        #pragma unroll
        for (int j2 = 0; j2 < 4; ++j2)
            acc[i2][j2] = (f32x4){0.f, 0.f, 0.f, 0.f};

    const int NK = DIM_ / 32;   // 12

    #pragma unroll
    for (int c2 = 0; c2 < 2; ++c2) {
        const int blk = wv * 2 + c2;
        gload_lds16(bsrc + (size_t)(blk * 16 + brow_l) * DIM_ + bkof, &Bs[0][blk * 512]);
    }
    #pragma unroll
    for (int it = 0; it < 4; ++it) {
        const float4 v = *reinterpret_cast<const float4*>(arow[it]);
        ushort4 u4; u4.x = f2us(v.x); u4.y = f2us(v.y); u4.z = f2us(v.z); u4.w = f2us(v.w);
        *reinterpret_cast<ushort4*>(&As[0][it * 1024 + tid * 4]) = u4;
    }
    __syncthreads();

    for (int t = 0; t < NK; ++t) {
        const int cur = t & 1, nxt = cur ^ 1;
        const int kk = t * 32;
        float4 av[4];
        if (t + 1 < NK) {
            #pragma unroll
            for (int it = 0; it < 4; ++it)
                av[it] = *reinterpret_cast<const float4*>(arow[it] + kk + 32);
            #pragma unroll
            for (int c2 = 0; c2 < 2; ++c2) {
                const int blk = wv * 2 + c2;
                gload_lds16(bsrc + (size_t)(blk * 16 + brow_l) * DIM_ + kk + 32 + bkof,
                            &Bs[nxt][blk * 512]);
            }
        }
        bf16x8 af[4], bfm[4];
        #pragma unroll
        for (int rt = 0; rt < 4; ++rt)
            af[rt] = *reinterpret_cast<const bf16x8*>(&As[cur][(wm * 4 + rt) * 512 + lane * 8]);
        #pragma unroll
        for (int ct = 0; ct < 4; ++ct)
            bfm[ct] = *reinterpret_cast<const bf16x8*>(&Bs[cur][(wn * 4 + ct) * 512 + lane * 8]);
        #pragma unroll
        for (int rt = 0; rt < 4; ++rt)
            #pragma unroll
            for (int ct = 0; ct < 4; ++ct)
                acc[rt][ct] = __builtin_amdgcn_mfma_f32_16x16x32_bf16(af[rt], bfm[ct], acc[rt][ct], 0, 0, 0);
        if (t + 1 < NK) {
            #pragma unroll
            for (int it = 0; it < 4; ++it) {
                ushort4 u4;
                u4.x = f2us(av[it].x); u4.y = f2us(av[it].y);
                u4.z = f2us(av[it].z); u4.w = f2us(av[it].w);
                *reinterpret_cast<ushort4*>(&As[nxt][it * 1024 + tid * 4]) = u4;
            }
        }
        __syncthreads();
    }

    // epilogue: bias, scale(Q), scatter to qws/kws/vws layouts
    const int lw = mb * 2 + wm;
    const float scale = 0.17677669529663687f;  // 32^-0.5
    const ushort* bias_all = wb + 589824 + wsel * 384;
    #pragma unroll
    for (int ct = 0; ct < 4; ++ct) {
        const int jl = ntm * 128 + wn * 64 + ct * 16 + col16;
        const int head = jl >> 5, hd = jl & 31;
        const float bj = bf2f_us(bias_all[jl]);
        #pragma unroll
        for (int rt = 0; rt < 4; ++rt) {
            if (wsel == 2) {
                ushort4 pk;
                pk.x = f2us(acc[rt][ct][0] + bj);
                pk.y = f2us(acc[rt][ct][1] + bj);
                pk.z = f2us(acc[rt][ct][2] + bj);
                pk.w = f2us(acc[rt][ct][3] + bj);
                *reinterpret_cast<ushort4*>(
                    vws + ((size_t)(lw * NH_ + head) * 32 + hd) * 64 + rt * 16 + quad * 4) = pk;
            } else {
                #pragma unroll
                for (int r = 0; r < 4; ++r) {
                    const int token = rt * 16 + quad * 4 + r;
                    const float v = acc[rt][ct][r] + bj;
                    if (wsel == 0)
                        qws[((size_t)(lw * NH_ + head) * 64 + token) * 32 + hd] = f2us(v * scale);
                    else
                        kws[((size_t)(lw * NH_ + head) * 64 + token) * 32 + hd] = f2us(v);
                }
            }
        }
    }
}

// ---------------- windowed attention: 4 heads (4 waves) per block, no barrier ----------------
__global__ __launch_bounds__(256) void attn_kernel(
    const __hip_bfloat16* __restrict__ qws, const __hip_bfloat16* __restrict__ kws,
    const __hip_bfloat16* __restrict__ vws, const float* __restrict__ biasv,
    __hip_bfloat16* __restrict__ attnout, int wbase)
{
    __shared__ __align__(16) ushort Pbuf[4][64 * 72];
    const int bid = blockIdx.x;
    const int lw = bid / 3, hg = bid - lw * 3;
    const int tid = threadIdx.x, wvi = tid >> 6, lane = tid & 63;
    const int h = hg * 4 + wvi;
    const int w = wbase + lw;
    const int col16 = lane & 15, quad = lane >> 4;
    const ushort* qp = reinterpret_cast<const ushort*>(qws) + ((size_t)lw * NH_ + h) * 64 * 32;
    const ushort* kp = reinterpret_cast<const ushort*>(kws) + ((size_t)lw * NH_ + h) * 64 * 32;
    const ushort* vp = reinterpret_cast<const ushort*>(vws) + ((size_t)lw * NH_ + h) * 32 * 64;

    bf16x8 aq[4], bk4[4];
    #pragma unroll
    for (int t = 0; t < 4; ++t) {
        aq[t]  = *reinterpret_cast<const bf16x8*>(qp + (t * 16 + col16) * 32 + quad * 8);
        bk4[t] = *reinterpret_cast<const bf16x8*>(kp + (t * 16 + col16) * 32 + quad * 8);
    }
    f32x4 S[4][4];
    #pragma unroll
    for (int rt = 0; rt < 4; ++rt) {
        #pragma unroll
        for (int ct = 0; ct < 4; ++ct) {
            f32x4 z = {0.f,0.f,0.f,0.f};
            S[rt][ct] = __builtin_amdgcn_mfma_f32_16x16x32_bf16(aq[rt], bk4[ct], z, 0, 0, 0);
        }
    }

    // pre-masked bias in C-fragment layout: one float4 per (rt,ct)
    const int widx = w & 63, wr = widx >> 3, wc = widx & 7;
    const int v = ((wr == 7) ? 2 : 0) + ((wc == 7) ? 1 : 0);
    const float4* bp = reinterpret_cast<const float4*>(biasv) +
                       ((size_t)(v * NH_ + h) * 16) * 64 + lane;
    #pragma unroll
    for (int rt = 0; rt < 4; ++rt) {
        #pragma unroll
        for (int ct = 0; ct < 4; ++ct) {
            const float4 bb = bp[(rt * 4 + ct) * 64];
            S[rt][ct][0] += bb.x; S[rt][ct][1] += bb.y;
            S[rt][ct][2] += bb.z; S[rt][ct][3] += bb.w;
        }
    }

    ushort* pb_w = &Pbuf[wvi][0];
    #pragma unroll
    for (int rt = 0; rt < 4; ++rt) {
        float rm[4], rs[4];
        #pragma unroll
        for (int r = 0; r < 4; ++r)
            rm[r] = fmaxf(fmaxf(S[rt][0][r], S[rt][1][r]), fmaxf(S[rt][2][r], S[rt][3][r]));
        #pragma unroll
        for (int d = 1; d <= 8; d <<= 1) {
            #pragma unroll
            for (int r = 0; r < 4; ++r) rm[r] = fmaxf(rm[r], __shfl_xor(rm[r], d, 64));
        }
        #pragma unroll
        for (int r = 0; r < 4; ++r) rs[r] = 0.f;
        #pragma unroll
        for (int ct = 0; ct < 4; ++ct) {
            #pragma unroll
            for (int r = 0; r < 4; ++r) {
                float p = __expf(S[rt][ct][r] - rm[r]);
                S[rt][ct][r] = p;
                rs[r] += p;
            }
        }
        #pragma unroll
        for (int d = 1; d <= 8; d <<= 1) {
            #pragma unroll
            for (int r = 0; r < 4; ++r) rs[r] += __shfl_xor(rs[r], d, 64);
        }
        #pragma unroll
        for (int ct = 0; ct < 4; ++ct) {
            #pragma unroll
            for (int r = 0; r < 4; ++r) {
                const float inv = 1.0f / rs[r];
                pb_w[(rt * 16 + quad * 4 + r) * 72 + ct * 16 + col16] =
                    f2us(S[rt][ct][r] * inv);
            }
        }
    }
    // Pbuf is per-wave: no __syncthreads needed (RAW within wave via lgkmcnt)

    f32x4 O[4][2];
    #pragma unroll
    for (int rt = 0; rt < 4; ++rt) {
        f32x4 z = {0.f,0.f,0.f,0.f};
        O[rt][0] = z; O[rt][1] = z;
    }
    #pragma unroll
    for (int ks = 0; ks < 2; ++ks) {
        bf16x8 bv0 = *reinterpret_cast<const bf16x8*>(vp + (col16)*64 + ks * 32 + quad * 8);
        bf16x8 bv1 = *reinterpret_cast<const bf16x8*>(vp + (16 + col16) * 64 + ks * 32 + quad * 8);
        #pragma unroll
        for (int rt = 0; rt < 4; ++rt) {
            bf16x8 ap = *reinterpret_cast<const bf16x8*>(pb_w + (rt * 16 + col16) * 72 + ks * 32 + quad * 8);
            O[rt][0] = __builtin_amdgcn_mfma_f32_16x16x32_bf16(ap, bv0, O[rt][0], 0, 0, 0);
            O[rt][1] = __builtin_amdgcn_mfma_f32_16x16x32_bf16(ap, bv1, O[rt][1], 0, 0, 0);
        }
    }
    __hip_bfloat16* op = attnout + (size_t)lw * 64 * DIM_ + h * 32;
    #pragma unroll
    for (int rt = 0; rt < 4; ++rt) {
        #pragma unroll
        for (int c2 = 0; c2 < 2; ++c2) {
            #pragma unroll
            for (int r = 0; r < 4; ++r) {
                const int token = rt * 16 + quad * 4 + r;
                op[token * DIM_ + c2 * 16 + col16] = __float2bfloat16(O[rt][c2][r]);
            }
        }
    }
}

// ---------------- output projection as 128x128x(BK=32) GEMM ----------------
__global__ __launch_bounds__(256, 4) void proj_gemm(
    const ushort* __restrict__ attnin, const ushort* __restrict__ wb,
    float* __restrict__ out, int wbase, int nmb)
{
    __shared__ __align__(16) ushort As[2][4096];
    __shared__ __align__(16) ushort Bs[2][4096];
    const int nwg = nmb * 3;
    const int orig = blockIdx.x;
    const int wgid = (orig & 7) * (nwg >> 3) + (orig >> 3);
    const int mb = wgid / 3, nt = wgid - mb * 3;
    const int n0 = nt * 128;
    const int tid = threadIdx.x, lane = tid & 63, wv = tid >> 6;
    const int col16 = lane & 15, quad = lane >> 4;
    const int wm = wv >> 1, wn = wv & 1;

    const ushort* asrc = attnin + (size_t)mb * 128 * DIM_;
    const ushort* bsrc = wb + (size_t)3 * 147456 + (size_t)n0 * DIM_;
    const int row_l = lane & 15, kof_l = (lane >> 4) * 8;

    f32x4 acc[4][4];
    #pragma unroll
    for (int i2 = 0; i2 < 4; ++i2)
        #pragma unroll
        for (int j2 = 0; j2 < 4; ++j2)
            acc[i2][j2] = (f32x4){0.f, 0.f, 0.f, 0.f};

    const int NK = DIM_ / 32;

    #pragma unroll
    for (int c2 = 0; c2 < 2; ++c2) {
        const int blk = wv * 2 + c2;
        gload_lds16(asrc + (size_t)(blk * 16 + row_l) * DIM_ + kof_l, &As[0][blk * 512]);
        gload_lds16(bsrc + (size_t)(blk * 16 + row_l) * DIM_ + kof_l, &Bs[0][blk * 512]);
    }
    __syncthreads();

    for (int t = 0; t < NK; ++t) {
        const int cur = t & 1, nxt = cur ^ 1;
        const int kk = t * 32;
        if (t + 1 < NK) {
            #pragma unroll
            for (int c2 = 0; c2 < 2; ++c2) {
                const int blk = wv * 2 + c2;
                gload_lds16(asrc + (size_t)(blk * 16 + row_l) * DIM_ + kk + 32 + kof_l,
                            &As[nxt][blk * 512]);
                gload_lds16(bsrc + (size_t)(blk * 16 + row_l) * DIM_ + kk + 32 + kof_l,
                            &Bs[nxt][blk * 512]);
            }
        }
        bf16x8 af[4], bfm[4];
        #pragma unroll
        for (int rt = 0; rt < 4; ++rt)
            af[rt] = *reinterpret_cast<const bf16x8*>(&As[cur][(wm * 4 + rt) * 512 + lane * 8]);
        #pragma unroll
        for (int ct = 0; ct < 4; ++ct)
            bfm[ct] = *reinterpret_cast<const bf16x8*>(&Bs[cur][(wn * 4 + ct) * 512 + lane * 8]);
        #pragma unroll
        for (int rt = 0; rt < 4; ++rt)
            #pragma unroll
            for (int ct = 0; ct < 4; ++ct)
                acc[rt][ct] = __builtin_amdgcn_mfma_f32_16x16x32_bf16(af[rt], bfm[ct], acc[rt][ct], 0, 0, 0);
        __syncthreads();
    }

    const int lw = mb * 2 + wm;
    const int wglob = wbase + lw;
    const int b = wglob >> 6, widx = wglob & 63, wr = widx >> 3, wc = widx & 7;
    const ushort* boc = wb + 589824 + 3 * 384;
    #pragma unroll
    for (int ct = 0; ct < 4; ++ct) {
        const int j = n0 + wn * 64 + ct * 16 + col16;
        const float bj = bf2f_us(boc[j]);
        #pragma unroll
        for (int rt = 0; rt < 4; ++rt) {
            #pragma unroll
            for (int r = 0; r < 4; ++r) {
                const int token = rt * 16 + quad * 4 + r;
                const int orr = (wr * 8 + (token >> 3) + 4) & 63;
                const int occ = (wc * 8 + (token & 7) + 4) & 63;
                out[(((size_t)b * 64 + orr) * 64 + occ) * DIM_ + j] = acc[rt][ct][r] + bj;
            }
        }
    }
}

extern "C" void kernel_launch(void* const* d_in, const int* in_sizes, int n_in,
                              void* d_out, int out_size, void* d_ws, size_t ws_size,
                              hipStream_t stream) {
    const float* x = (const float*)d_in[0];
    float* out = (float*)d_out;
    char* ws = (char*)d_ws;

    // ws layout (bytes):
    //   0        : ushort[594060] bf16 weights/biases/table (1,188,120 B)
    //   1188352  : float biasv[4*12*16*64*4]  (786,432 B) pre-masked C-fragment bias
    //   1974784  : chunk buffers qws|kws|vws|att (each WCHUNK*49152 B)
    ushort* wb    = (ushort*)ws;
    float*  biasv = (float*)(ws + 1188352);
    const size_t FIXED = 1974784;

    int wchunk = 128;
    const int cands[4] = {2048, 1024, 512, 256};
    for (int i = 0; i < 4; ++i) {
        if (FIXED + (size_t)cands[i] * 4 * 49152 <= ws_size) { wchunk = cands[i]; break; }
    }
    const size_t CQ = (size_t)wchunk * NH_ * 64 * 32 * 2;
    __hip_bfloat16* qws = (__hip_bfloat16*)(ws + FIXED);
    __hip_bfloat16* kws = (__hip_bfloat16*)(ws + FIXED + CQ);
    __hip_bfloat16* vws = (__hip_bfloat16*)(ws + FIXED + 2 * CQ);
    __hip_bfloat16* att = (__hip_bfloat16*)(ws + FIXED + 3 * CQ);

    convert_kernel<<<dim3(512), dim3(256), 0, stream>>>(
        (const float*)d_in[1], (const float*)d_in[3], (const float*)d_in[5], (const float*)d_in[7],
        (const float*)d_in[2], (const float*)d_in[4], (const float*)d_in[6], (const float*)d_in[8],
        (const float*)d_in[9], wb);
    bias_kernel<<<dim3(48), dim3(256), 0, stream>>>(wb + 591360, biasv);

    for (int c = 0; c < 2048 / wchunk; ++c) {
        const int wbase = c * wchunk;
        const int nmb = wchunk / 2;
        qkv_gemm<<<dim3(nmb * 9), dim3(256), 0, stream>>>(
            x, wb, (ushort*)qws, (ushort*)kws, (ushort*)vws, wbase, nmb);
        attn_kernel<<<dim3(wchunk * 3), dim3(256), 0, stream>>>(
            qws, kws, vws, biasv, att, wbase);
        proj_gemm<<<dim3(nmb * 3), dim3(256), 0, stream>>>(
            (const ushort*)att, wb, out, wbase, nmb);
    }
}

// Round 5
// 785.991 us; speedup vs baseline: 1.1037x; 1.1037x over previous
//
#include <hip/hip_runtime.h>
#include <hip/hip_bf16.h>

typedef short bf16x8 __attribute__((ext_vector_type(8)));
typedef float f32x4 __attribute__((ext_vector_type(4)));

#define NH_ 12
#define DIM_ 384

static __device__ __forceinline__ float bf2f_us(ushort u) {
    __hip_bfloat16 h; __builtin_memcpy(&h, &u, 2);
    return __bfloat162float(h);
}
static __device__ __forceinline__ ushort f2us(float f) {
    __hip_bfloat16 h = __float2bfloat16(f);
    ushort u; __builtin_memcpy(&u, &h, 2);
    return u;
}

// async global->LDS, 16B per lane; LDS dest = base + lane*16 (wave-uniform base)
static __device__ __forceinline__ void gload_lds16(const void* g, void* l) {
    __builtin_amdgcn_global_load_lds(
        (const __attribute__((address_space(1))) unsigned int*)g,
        (__attribute__((address_space(3))) unsigned int*)l, 16, 0, 0);
}

static __device__ __forceinline__ int regioncnt(int t, int wr, int wc) {
    int rr = (wr == 7) ? (((t >> 3) < 4) ? 1 : 2) : 0;
    int cc = (wc == 7) ? (((t & 7) < 4) ? 1 : 2) : 0;
    return rr * 3 + cc;
}

// Fragment-linear tile layout ("P1"): a 128-row x K tile is stored as
//   [t = k>>5][rb = row>>4][slot l = ((k>>3)&3)*16 + (row&15)][e = k&7]
// ushort idx = t*4096 + rb*512 + l*8 + e. A wave's MFMA fragment read for
// subtile rb is the contiguous 1024B block [rb*512 .. +512) at lane*16 offsets,
// and global_load_lds staging of one rb-block is 64 lanes * 16B contiguous.

// ---------------- convert f32 weights/biases/table -> bf16 (weights in P1 tiles) --------
// dst: 12 tiles (9 qkv [wq|wk|wv] + 3 wo) * 49152 ushorts | biases at 589824 | table 591360
__global__ __launch_bounds__(256) void convert_kernel(
    const float* wq, const float* wk, const float* wv, const float* wo,
    const float* bq, const float* bk, const float* bv, const float* bo,
    const float* bt, ushort* __restrict__ dst)
{
    const int N = 594060;
    for (int i = blockIdx.x * 256 + threadIdx.x; i < N; i += gridDim.x * 256) {
        if (i < 589824) {
            const int nt12 = i / 49152;
            const int j = i - nt12 * 49152;
            const int t = j >> 12, rb = (j >> 9) & 7, l = (j >> 3) & 63, e = j & 7;
            const int row128 = rb * 16 + (l & 15);
            const int k = t * 32 + ((l >> 4) << 3) + e;
            const float* src; int row;
            if (nt12 < 9) {
                const int wsel = nt12 / 3;
                src = (wsel == 0) ? wq : (wsel == 1) ? wk : wv;
                row = (nt12 - wsel * 3) * 128 + row128;
            } else {
                src = wo; row = (nt12 - 9) * 128 + row128;
            }
            dst[i] = f2us(src[row * 384 + k]);
        } else if (i < 591360) {
            const int bsel = (i - 589824) / 384;
            const int off = (i - 589824) - bsel * 384;
            const float* src = (bsel == 0) ? bq : (bsel == 1) ? bk : (bsel == 2) ? bv : bo;
            dst[i] = f2us(src[off]);
        } else {
            dst[i] = f2us(bt[i - 591360]);
        }
    }
}

// ---------------- pre-masked bias in C-fragment layout ----------------
__global__ __launch_bounds__(256) void bias_kernel(
    const ushort* __restrict__ tablec, float* __restrict__ biasv)
{
    const int vh = blockIdx.x;                 // 0..47 = v*NH_ + h
    const int v = vh / NH_, h = vh - v * NH_;
    const int wr = (v & 2) ? 7 : 0, wc = (v & 1) ? 7 : 0;
    const int tid = threadIdx.x, lane = tid & 63;
    #pragma unroll
    for (int i = 0; i < 4; ++i) {
        const int tno = (tid >> 6) + 4 * i;    // 0..15
        const int rt = tno >> 2, ct = tno & 3;
        const int jj = ct * 16 + (lane & 15);
        const int cntj = regioncnt(jj, wr, wc);
        float4 o;
        float vals[4];
        #pragma unroll
        for (int r = 0; r < 4; ++r) {
            const int ii = rt * 16 + (lane >> 4) * 4 + r;
            const int idx = ((ii >> 3) - (jj >> 3) + 7) * 15 + ((ii & 7) - (jj & 7) + 7);
            float val = bf2f_us(tablec[idx * NH_ + h]);
            if (regioncnt(ii, wr, wc) != cntj) val -= 100.f;
            vals[r] = val;
        }
        o.x = vals[0]; o.y = vals[1]; o.z = vals[2]; o.w = vals[3];
        reinterpret_cast<float4*>(biasv)[((size_t)vh * 16 + tno) * 64 + lane] = o;
    }
}

// ---------------- gather x (roll + window partition) -> bf16 in P1 M-tiles ----------------
__global__ __launch_bounds__(256) void xprep_kernel(
    const float* __restrict__ x, ushort* __restrict__ xc, int wbase, int nmb)
{
    const int mb = blockIdx.x;
    const int tid = threadIdx.x;
    ushort* outp = xc + (size_t)mb * 49152;
    #pragma unroll 4
    for (int it = 0; it < 48; ++it) {
        const int g = it * 256 + tid;
        const int row = g / 96, f4 = g - row * 96;   // row 0..127, f4 0..95 (float4 in row)
        const int wglob = wbase + mb * 2 + (row >> 6);
        const int token = row & 63;
        const int b = wglob >> 6, widx = wglob & 63, wr = widx >> 3, wc = widx & 7;
        const int orr = (wr * 8 + (token >> 3) + 4) & 63;
        const int occ = (wc * 8 + (token & 7) + 4) & 63;
        const float4 v = *reinterpret_cast<const float4*>(
            x + (((size_t)b * 64 + orr) * 64 + occ) * DIM_ + f4 * 4);
        ushort4 u4; u4.x = f2us(v.x); u4.y = f2us(v.y); u4.z = f2us(v.z); u4.w = f2us(v.w);
        const int idx = (f4 >> 3) * 4096 + (row >> 4) * 512 +
                        ((f4 >> 1) & 3) * 128 + (row & 15) * 8 + (f4 & 1) * 4;
        *reinterpret_cast<ushort4*>(outp + idx) = u4;
    }
}

// ---------------- QKV projection: pure gload_lds GEMM, 3-deep counted-vmcnt pipeline ------
__global__ __launch_bounds__(256, 3) void qkv_gemm(
    const ushort* __restrict__ xc, const ushort* __restrict__ wb,
    ushort* __restrict__ qws, ushort* __restrict__ kws, ushort* __restrict__ vws,
    int nmb)
{
    __shared__ __align__(16) ushort As[3][4096];
    __shared__ __align__(16) ushort Bs[3][4096];
    const int nwg = nmb * 9;
    const int orig = blockIdx.x;
    const int wgid = (orig & 7) * (nwg >> 3) + (orig >> 3);   // XCD-chunked (nwg%8==0)
    const int mb = wgid / 9, nt = wgid - mb * 9;
    const int wsel = nt / 3, ntm = nt - wsel * 3;
    const int tid = threadIdx.x, lane = tid & 63, wv = tid >> 6;
    const int col16 = lane & 15, quad = lane >> 4;
    const int wm = wv >> 1, wn = wv & 1;

    const ushort* asrc = xc + (size_t)mb * 49152 + lane * 8;
    const ushort* bsrc = wb + (size_t)nt * 49152 + lane * 8;

    f32x4 acc[4][4];
    #pragma unroll
    for (int i2 = 0; i2 < 4; ++i2)
        #pragma unroll
        for (int j2 = 0; j2 < 4; ++j2)
            acc[i2][j2] = (f32x4){0.f, 0.f, 0.f, 0.f};

    #define STAGE(T, BUF)                                                        \
        gload_lds16(asrc + (T)*4096 + (2*wv)*512,   &As[BUF][(2*wv)*512]);       \
        gload_lds16(asrc + (T)*4096 + (2*wv+1)*512, &As[BUF][(2*wv+1)*512]);     \
        gload_lds16(bsrc + (T)*4096 + (2*wv)*512,   &Bs[BUF][(2*wv)*512]);       \
        gload_lds16(bsrc + (T)*4096 + (2*wv+1)*512, &Bs[BUF][(2*wv+1)*512]);

    STAGE(0, 0)
    STAGE(1, 1)

    #pragma unroll
    for (int t = 0; t < 12; ++t) {
        // wait own 4 loads of tile t (4 of t+1 may stay in flight), then barrier
        if (t < 11) asm volatile("s_waitcnt vmcnt(4)" ::: "memory");
        else        asm volatile("s_waitcnt vmcnt(0)" ::: "memory");
        __builtin_amdgcn_s_barrier();
        if (t < 10) { STAGE(t + 2, (t + 2) % 3) }
        const int cur = t % 3;
        bf16x8 af[4], bfm[4];
        #pragma unroll
        for (int rt = 0; rt < 4; ++rt)
            af[rt] = *reinterpret_cast<const bf16x8*>(&As[cur][(wm * 4 + rt) * 512 + lane * 8]);
        #pragma unroll
        for (int ct = 0; ct < 4; ++ct)
            bfm[ct] = *reinterpret_cast<const bf16x8*>(&Bs[cur][(wn * 4 + ct) * 512 + lane * 8]);
        #pragma unroll
        for (int rt = 0; rt < 4; ++rt)
            #pragma unroll
            for (int ct = 0; ct < 4; ++ct)
                acc[rt][ct] = __builtin_amdgcn_mfma_f32_16x16x32_bf16(af[rt], bfm[ct], acc[rt][ct], 0, 0, 0);
        // ensure this tile's ds_reads are complete before next step's stage overwrites
        asm volatile("s_waitcnt lgkmcnt(0)" ::: "memory");
    }
    #undef STAGE

    // epilogue: bias, scale(Q), scatter to qws/kws/vws layouts
    const int lw = mb * 2 + wm;
    const float scale = 0.17677669529663687f;  // 32^-0.5
    const ushort* bias_all = wb + 589824 + wsel * 384;
    #pragma unroll
    for (int ct = 0; ct < 4; ++ct) {
        const int jl = ntm * 128 + wn * 64 + ct * 16 + col16;
        const int head = jl >> 5, hd = jl & 31;
        const float bj = bf2f_us(bias_all[jl]);
        #pragma unroll
        for (int rt = 0; rt < 4; ++rt) {
            if (wsel == 2) {
                ushort4 pk;
                pk.x = f2us(acc[rt][ct][0] + bj);
                pk.y = f2us(acc[rt][ct][1] + bj);
                pk.z = f2us(acc[rt][ct][2] + bj);
                pk.w = f2us(acc[rt][ct][3] + bj);
                *reinterpret_cast<ushort4*>(
                    vws + ((size_t)(lw * NH_ + head) * 32 + hd) * 64 + rt * 16 + quad * 4) = pk;
            } else {
                #pragma unroll
                for (int r = 0; r < 4; ++r) {
                    const int token = rt * 16 + quad * 4 + r;
                    const float v = acc[rt][ct][r] + bj;
                    if (wsel == 0)
                        qws[((size_t)(lw * NH_ + head) * 64 + token) * 32 + hd] = f2us(v * scale);
                    else
                        kws[((size_t)(lw * NH_ + head) * 64 + token) * 32 + hd] = f2us(v);
                }
            }
        }
    }
}

// ---------------- windowed attention: 4 heads (4 waves) per block ----------------
// Output written directly in P1 M-tile layout (head h's 32 dims == K-step h).
__global__ __launch_bounds__(256) void attn_kernel(
    const __hip_bfloat16* __restrict__ qws, const __hip_bfloat16* __restrict__ kws,
    const __hip_bfloat16* __restrict__ vws, const float* __restrict__ biasv,
    ushort* __restrict__ attnout, int wbase)
{
    __shared__ __align__(16) ushort Pbuf[4][64 * 72];
    const int bid = blockIdx.x;
    const int lw = bid / 3, hg = bid - lw * 3;
    const int tid = threadIdx.x, wvi = tid >> 6, lane = tid & 63;
    const int h = hg * 4 + wvi;
    const int w = wbase + lw;
    const int col16 = lane & 15, quad = lane >> 4;
    const ushort* qp = reinterpret_cast<const ushort*>(qws) + ((size_t)lw * NH_ + h) * 64 * 32;
    const ushort* kp = reinterpret_cast<const ushort*>(kws) + ((size_t)lw * NH_ + h) * 64 * 32;
    const ushort* vp = reinterpret_cast<const ushort*>(vws) + ((size_t)lw * NH_ + h) * 32 * 64;

    bf16x8 aq[4], bk4[4];
    #pragma unroll
    for (int t = 0; t < 4; ++t) {
        aq[t]  = *reinterpret_cast<const bf16x8*>(qp + (t * 16 + col16) * 32 + quad * 8);
        bk4[t] = *reinterpret_cast<const bf16x8*>(kp + (t * 16 + col16) * 32 + quad * 8);
    }
    f32x4 S[4][4];
    #pragma unroll
    for (int rt = 0; rt < 4; ++rt) {
        #pragma unroll
        for (int ct = 0; ct < 4; ++ct) {
            f32x4 z = {0.f,0.f,0.f,0.f};
            S[rt][ct] = __builtin_amdgcn_mfma_f32_16x16x32_bf16(aq[rt], bk4[ct], z, 0, 0, 0);
        }
    }

    const int widx = w & 63, wr = widx >> 3, wc = widx & 7;
    const int v = ((wr == 7) ? 2 : 0) + ((wc == 7) ? 1 : 0);
    const float4* bp = reinterpret_cast<const float4*>(biasv) +
                       ((size_t)(v * NH_ + h) * 16) * 64 + lane;
    #pragma unroll
    for (int rt = 0; rt < 4; ++rt) {
        #pragma unroll
        for (int ct = 0; ct < 4; ++ct) {
            const float4 bb = bp[(rt * 4 + ct) * 64];
            S[rt][ct][0] += bb.x; S[rt][ct][1] += bb.y;
            S[rt][ct][2] += bb.z; S[rt][ct][3] += bb.w;
        }
    }

    ushort* pb_w = &Pbuf[wvi][0];
    #pragma unroll
    for (int rt = 0; rt < 4; ++rt) {
        float rm[4], rs[4];
        #pragma unroll
        for (int r = 0; r < 4; ++r)
            rm[r] = fmaxf(fmaxf(S[rt][0][r], S[rt][1][r]), fmaxf(S[rt][2][r], S[rt][3][r]));
        #pragma unroll
        for (int d = 1; d <= 8; d <<= 1) {
            #pragma unroll
            for (int r = 0; r < 4; ++r) rm[r] = fmaxf(rm[r], __shfl_xor(rm[r], d, 64));
        }
        #pragma unroll
        for (int r = 0; r < 4; ++r) rs[r] = 0.f;
        #pragma unroll
        for (int ct = 0; ct < 4; ++ct) {
            #pragma unroll
            for (int r = 0; r < 4; ++r) {
                float p = __expf(S[rt][ct][r] - rm[r]);
                S[rt][ct][r] = p;
                rs[r] += p;
            }
        }
        #pragma unroll
        for (int d = 1; d <= 8; d <<= 1) {
            #pragma unroll
            for (int r = 0; r < 4; ++r) rs[r] += __shfl_xor(rs[r], d, 64);
        }
        #pragma unroll
        for (int ct = 0; ct < 4; ++ct) {
            #pragma unroll
            for (int r = 0; r < 4; ++r) {
                const float inv = 1.0f / rs[r];
                pb_w[(rt * 16 + quad * 4 + r) * 72 + ct * 16 + col16] =
                    f2us(S[rt][ct][r] * inv);
            }
        }
    }
    // Pbuf is per-wave: no barrier needed

    f32x4 O[4][2];
    #pragma unroll
    for (int rt = 0; rt < 4; ++rt) {
        f32x4 z = {0.f,0.f,0.f,0.f};
        O[rt][0] = z; O[rt][1] = z;
    }
    #pragma unroll
    for (int ks = 0; ks < 2; ++ks) {
        bf16x8 bv0 = *reinterpret_cast<const bf16x8*>(vp + (col16)*64 + ks * 32 + quad * 8);
        bf16x8 bv1 = *reinterpret_cast<const bf16x8*>(vp + (16 + col16) * 64 + ks * 32 + quad * 8);
        #pragma unroll
        for (int rt = 0; rt < 4; ++rt) {
            bf16x8 ap = *reinterpret_cast<const bf16x8*>(pb_w + (rt * 16 + col16) * 72 + ks * 32 + quad * 8);
            O[rt][0] = __builtin_amdgcn_mfma_f32_16x16x32_bf16(ap, bv0, O[rt][0], 0, 0, 0);
            O[rt][1] = __builtin_amdgcn_mfma_f32_16x16x32_bf16(ap, bv1, O[rt][1], 0, 0, 0);
        }
    }
    // store O in P1 tile layout: tile mb=lw>>1, step t=h, rb=(lw&1)*4+rt
    ushort* op = attnout + (size_t)(lw >> 1) * 49152 + (size_t)h * 4096 + (lw & 1) * 2048;
    const int elo = col16 & 7;
    #pragma unroll
    for (int rt = 0; rt < 4; ++rt) {
        #pragma unroll
        for (int c2 = 0; c2 < 2; ++c2) {
            const int kch = c2 * 2 + (col16 >> 3);
            #pragma unroll
            for (int r = 0; r < 4; ++r) {
                op[rt * 512 + kch * 128 + (quad * 4 + r) * 8 + elo] = f2us(O[rt][c2][r]);
            }
        }
    }
}

// ---------------- output projection: pure gload_lds GEMM, 3-deep pipeline ----------------
__global__ __launch_bounds__(256, 3) void proj_gemm(
    const ushort* __restrict__ attnin, const ushort* __restrict__ wb,
    float* __restrict__ out, int wbase, int nmb)
{
    __shared__ __align__(16) ushort As[3][4096];
    __shared__ __align__(16) ushort Bs[3][4096];
    const int nwg = nmb * 3;
    const int orig = blockIdx.x;
    const int wgid = (orig & 7) * (nwg >> 3) + (orig >> 3);
    const int mb = wgid / 3, nt = wgid - mb * 3;
    const int tid = threadIdx.x, lane = tid & 63, wv = tid >> 6;
    const int col16 = lane & 15, quad = lane >> 4;
    const int wm = wv >> 1, wn = wv & 1;

    const ushort* asrc = attnin + (size_t)mb * 49152 + lane * 8;
    const ushort* bsrc = wb + (size_t)(9 + nt) * 49152 + lane * 8;

    f32x4 acc[4][4];
    #pragma unroll
    for (int i2 = 0; i2 < 4; ++i2)
        #pragma unroll
        for (int j2 = 0; j2 < 4; ++j2)
            acc[i2][j2] = (f32x4){0.f, 0.f, 0.f, 0.f};

    #define STAGE(T, BUF)                                                        \
        gload_lds16(asrc + (T)*4096 + (2*wv)*512,   &As[BUF][(2*wv)*512]);       \
        gload_lds16(asrc + (T)*4096 + (2*wv+1)*512, &As[BUF][(2*wv+1)*512]);     \
        gload_lds16(bsrc + (T)*4096 + (2*wv)*512,   &Bs[BUF][(2*wv)*512]);       \
        gload_lds16(bsrc + (T)*4096 + (2*wv+1)*512, &Bs[BUF][(2*wv+1)*512]);

    STAGE(0, 0)
    STAGE(1, 1)

    #pragma unroll
    for (int t = 0; t < 12; ++t) {
        if (t < 11) asm volatile("s_waitcnt vmcnt(4)" ::: "memory");
        else        asm volatile("s_waitcnt vmcnt(0)" ::: "memory");
        __builtin_amdgcn_s_barrier();
        if (t < 10) { STAGE(t + 2, (t + 2) % 3) }
        const int cur = t % 3;
        bf16x8 af[4], bfm[4];
        #pragma unroll
        for (int rt = 0; rt < 4; ++rt)
            af[rt] = *reinterpret_cast<const bf16x8*>(&As[cur][(wm * 4 + rt) * 512 + lane * 8]);
        #pragma unroll
        for (int ct = 0; ct < 4; ++ct)
            bfm[ct] = *reinterpret_cast<const bf16x8*>(&Bs[cur][(wn * 4 + ct) * 512 + lane * 8]);
        #pragma unroll
        for (int rt = 0; rt < 4; ++rt)
            #pragma unroll
            for (int ct = 0; ct < 4; ++ct)
                acc[rt][ct] = __builtin_amdgcn_mfma_f32_16x16x32_bf16(af[rt], bfm[ct], acc[rt][ct], 0, 0, 0);
        asm volatile("s_waitcnt lgkmcnt(0)" ::: "memory");
    }
    #undef STAGE

    const int lw = mb * 2 + wm;
    const int wglob = wbase + lw;
    const int b = wglob >> 6, widx = wglob & 63, wr = widx >> 3, wc = widx & 7;
    const ushort* boc = wb + 589824 + 3 * 384;
    #pragma unroll
    for (int ct = 0; ct < 4; ++ct) {
        const int j = nt * 128 + wn * 64 + ct * 16 + col16;
        const float bj = bf2f_us(boc[j]);
        #pragma unroll
        for (int rt = 0; rt < 4; ++rt) {
            #pragma unroll
            for (int r = 0; r < 4; ++r) {
                const int token = rt * 16 + quad * 4 + r;
                const int orr = (wr * 8 + (token >> 3) + 4) & 63;
                const int occ = (wc * 8 + (token & 7) + 4) & 63;
                out[(((size_t)b * 64 + orr) * 64 + occ) * DIM_ + j] = acc[rt][ct][r] + bj;
            }
        }
    }
}

extern "C" void kernel_launch(void* const* d_in, const int* in_sizes, int n_in,
                              void* d_out, int out_size, void* d_ws, size_t ws_size,
                              hipStream_t stream) {
    const float* x = (const float*)d_in[0];
    float* out = (float*)d_out;
    char* ws = (char*)d_ws;

    // ws layout (bytes):
    //   0        : ushort[594060] bf16 weights(P1 tiles)/biases/table (1,188,120 B)
    //   1188352  : float biasv[4*12*16*64] float4s  (786,432 B) pre-masked C-fragment bias
    //   1974784  : chunk buffers xc(=att)|qws|kws|vws (each WCHUNK*49152 B)
    ushort* wb    = (ushort*)ws;
    float*  biasv = (float*)(ws + 1188352);
    const size_t FIXED = 1974784;

    int wchunk = 128;
    const int cands[4] = {2048, 1024, 512, 256};
    for (int i = 0; i < 4; ++i) {
        if (FIXED + (size_t)cands[i] * 4 * 49152 <= ws_size) { wchunk = cands[i]; break; }
    }
    const size_t CQ = (size_t)wchunk * 49152;
    ushort* xcatt = (ushort*)(ws + FIXED);                 // xprep tiles, later attn out
    ushort* qws   = (ushort*)(ws + FIXED + CQ);
    ushort* kws   = (ushort*)(ws + FIXED + 2 * CQ);
    ushort* vws   = (ushort*)(ws + FIXED + 3 * CQ);

    convert_kernel<<<dim3(512), dim3(256), 0, stream>>>(
        (const float*)d_in[1], (const float*)d_in[3], (const float*)d_in[5], (const float*)d_in[7],
        (const float*)d_in[2], (const float*)d_in[4], (const float*)d_in[6], (const float*)d_in[8],
        (const float*)d_in[9], wb);
    bias_kernel<<<dim3(48), dim3(256), 0, stream>>>(wb + 591360, biasv);

    for (int c = 0; c < 2048 / wchunk; ++c) {
        const int wbase = c * wchunk;
        const int nmb = wchunk / 2;
        xprep_kernel<<<dim3(nmb), dim3(256), 0, stream>>>(x, xcatt, wbase, nmb);
        qkv_gemm<<<dim3(nmb * 9), dim3(256), 0, stream>>>(
            xcatt, wb, qws, kws, vws, nmb);
        attn_kernel<<<dim3(wchunk * 3), dim3(256), 0, stream>>>(
            (const __hip_bfloat16*)qws, (const __hip_bfloat16*)kws,
            (const __hip_bfloat16*)vws, biasv, xcatt, wbase);
        proj_gemm<<<dim3(nmb * 3), dim3(256), 0, stream>>>(
            xcatt, wb, out, wbase, nmb);
    }
}

// Round 6
// 754.529 us; speedup vs baseline: 1.1498x; 1.0417x over previous
//
#include <hip/hip_runtime.h>
#include <hip/hip_bf16.h>

typedef short bf16x8 __attribute__((ext_vector_type(8)));
typedef float f32x4 __attribute__((ext_vector_type(4)));

#define NH_ 12
#define DIM_ 384

static __device__ __forceinline__ float bf2f_us(ushort u) {
    __hip_bfloat16 h; __builtin_memcpy(&h, &u, 2);
    return __bfloat162float(h);
}
static __device__ __forceinline__ ushort f2us(float f) {
    __hip_bfloat16 h = __float2bfloat16(f);
    ushort u; __builtin_memcpy(&u, &h, 2);
    return u;
}

// async global->LDS, 16B per lane; LDS dest = base + lane*16 (wave-uniform base)
static __device__ __forceinline__ void gload_lds16(const void* g, void* l) {
    __builtin_amdgcn_global_load_lds(
        (const __attribute__((address_space(1))) unsigned int*)g,
        (__attribute__((address_space(3))) unsigned int*)l, 16, 0, 0);
}

static __device__ __forceinline__ int regioncnt(int t, int wr, int wc) {
    int rr = (wr == 7) ? (((t >> 3) < 4) ? 1 : 2) : 0;
    int cc = (wc == 7) ? (((t & 7) < 4) ? 1 : 2) : 0;
    return rr * 3 + cc;
}

// Fragment-linear tile layout ("P1"): a R-row x K tile is stored as
//   [t = k>>5][rb = row>>4][slot l = ((k>>3)&3)*16 + (row&15)][e = k&7]
// ushort idx = t*(R*32) + rb*512 + l*8 + e. A wave's MFMA fragment read for
// subtile rb is the contiguous 1024B block [rb*512 .. +512) at lane*16 offsets,
// and global_load_lds staging of one rb-block is 64 lanes * 16B contiguous.
// Weights use R=128 (t-stride 4096); activations use R=256 (t-stride 8192).

// ---------------- convert f32 weights/biases/table -> bf16 (weights in P1 tiles) --------
// dst: 12 tiles (9 qkv [wq|wk|wv] + 3 wo) * 49152 ushorts | biases at 589824 | table 591360
__global__ __launch_bounds__(256) void convert_kernel(
    const float* wq, const float* wk, const float* wv, const float* wo,
    const float* bq, const float* bk, const float* bv, const float* bo,
    const float* bt, ushort* __restrict__ dst)
{
    const int N = 594060;
    for (int i = blockIdx.x * 256 + threadIdx.x; i < N; i += gridDim.x * 256) {
        if (i < 589824) {
            const int nt12 = i / 49152;
            const int j = i - nt12 * 49152;
            const int t = j >> 12, rb = (j >> 9) & 7, l = (j >> 3) & 63, e = j & 7;
            const int row128 = rb * 16 + (l & 15);
            const int k = t * 32 + ((l >> 4) << 3) + e;
            const float* src; int row;
            if (nt12 < 9) {
                const int wsel = nt12 / 3;
                src = (wsel == 0) ? wq : (wsel == 1) ? wk : wv;
                row = (nt12 - wsel * 3) * 128 + row128;
            } else {
                src = wo; row = (nt12 - 9) * 128 + row128;
            }
            dst[i] = f2us(src[row * 384 + k]);
        } else if (i < 591360) {
            const int bsel = (i - 589824) / 384;
            const int off = (i - 589824) - bsel * 384;
            const float* src = (bsel == 0) ? bq : (bsel == 1) ? bk : (bsel == 2) ? bv : bo;
            dst[i] = f2us(src[off]);
        } else {
            dst[i] = f2us(bt[i - 591360]);
        }
    }
}

// ---------------- pre-masked bias in C-fragment layout ----------------
__global__ __launch_bounds__(256) void bias_kernel(
    const ushort* __restrict__ tablec, float* __restrict__ biasv)
{
    const int vh = blockIdx.x;                 // 0..47 = v*NH_ + h
    const int v = vh / NH_, h = vh - v * NH_;
    const int wr = (v & 2) ? 7 : 0, wc = (v & 1) ? 7 : 0;
    const int tid = threadIdx.x, lane = tid & 63;
    #pragma unroll
    for (int i = 0; i < 4; ++i) {
        const int tno = (tid >> 6) + 4 * i;    // 0..15
        const int rt = tno >> 2, ct = tno & 3;
        const int jj = ct * 16 + (lane & 15);
        const int cntj = regioncnt(jj, wr, wc);
        float4 o;
        float vals[4];
        #pragma unroll
        for (int r = 0; r < 4; ++r) {
            const int ii = rt * 16 + (lane >> 4) * 4 + r;
            const int idx = ((ii >> 3) - (jj >> 3) + 7) * 15 + ((ii & 7) - (jj & 7) + 7);
            float val = bf2f_us(tablec[idx * NH_ + h]);
            if (regioncnt(ii, wr, wc) != cntj) val -= 100.f;
            vals[r] = val;
        }
        o.x = vals[0]; o.y = vals[1]; o.z = vals[2]; o.w = vals[3];
        reinterpret_cast<float4*>(biasv)[((size_t)vh * 16 + tno) * 64 + lane] = o;
    }
}

// ---------------- gather x (roll + window partition) -> bf16 in P1 256-row M-tiles -------
__global__ __launch_bounds__(256) void xprep_kernel(
    const float* __restrict__ x, ushort* __restrict__ xc, int wbase, int nmb)
{
    const int mb = blockIdx.x;
    const int tid = threadIdx.x;
    ushort* outp = xc + (size_t)mb * 98304;
    #pragma unroll 4
    for (int it = 0; it < 96; ++it) {
        const int g = it * 256 + tid;
        const int row = g / 96, f4 = g - row * 96;   // row 0..255, f4 0..95 (float4 in row)
        const int wglob = wbase + mb * 4 + (row >> 6);
        const int token = row & 63;
        const int b = wglob >> 6, widx = wglob & 63, wr = widx >> 3, wc = widx & 7;
        const int orr = (wr * 8 + (token >> 3) + 4) & 63;
        const int occ = (wc * 8 + (token & 7) + 4) & 63;
        const float4 v = *reinterpret_cast<const float4*>(
            x + (((size_t)b * 64 + orr) * 64 + occ) * DIM_ + f4 * 4);
        ushort4 u4; u4.x = f2us(v.x); u4.y = f2us(v.y); u4.z = f2us(v.z); u4.w = f2us(v.w);
        const int idx = (f4 >> 3) * 8192 + (row >> 4) * 512 +
                        ((f4 >> 1) & 3) * 128 + (row & 15) * 8 + (f4 & 1) * 4;
        *reinterpret_cast<ushort4*>(outp + idx) = u4;
    }
}

// ---------------- QKV projection: 256x128 tile, 8 waves, 3-deep counted-vmcnt ------------
__global__ __launch_bounds__(512, 4) void qkv_gemm(
    const ushort* __restrict__ xc, const ushort* __restrict__ wb,
    ushort* __restrict__ qws, ushort* __restrict__ kws, ushort* __restrict__ vws,
    int nmb)
{
    __shared__ __align__(16) ushort As[3][8192];   // 256 rows x 32 k per buffer
    __shared__ __align__(16) ushort Bs[3][4096];   // 128 rows x 32 k per buffer
    const int nwg = nmb * 9;
    const int orig = blockIdx.x;
    const int wgid = (orig & 7) * (nwg >> 3) + (orig >> 3);   // XCD-chunked (nwg%8==0)
    const int mb = wgid / 9, nt = wgid - mb * 9;
    const int wsel = nt / 3, ntm = nt - wsel * 3;
    const int tid = threadIdx.x, lane = tid & 63, wv = tid >> 6;  // wv 0..7
    const int col16 = lane & 15, quad = lane >> 4;
    const int wm = wv >> 1, wn = wv & 1;            // wave -> 64x64 quadrant (4M x 2N)

    const ushort* asrc = xc + (size_t)mb * 98304 + lane * 8;
    const ushort* bsrc = wb + (size_t)nt * 49152 + lane * 8;

    f32x4 acc[4][4];
    #pragma unroll
    for (int i2 = 0; i2 < 4; ++i2)
        #pragma unroll
        for (int j2 = 0; j2 < 4; ++j2)
            acc[i2][j2] = (f32x4){0.f, 0.f, 0.f, 0.f};

    // per wave per step: 2 A-blocks + 1 B-block = 3 gload_lds
    #define STAGE(T, BUF)                                                          \
        gload_lds16(asrc + (size_t)(T)*8192 + (2*wv)*512,   &As[BUF][(2*wv)*512]); \
        gload_lds16(asrc + (size_t)(T)*8192 + (2*wv+1)*512, &As[BUF][(2*wv+1)*512]);\
        gload_lds16(bsrc + (size_t)(T)*4096 + wv*512,       &Bs[BUF][wv*512]);

    STAGE(0, 0)
    STAGE(1, 1)

    #pragma unroll
    for (int t = 0; t < 12; ++t) {
        // wait own 3 loads of tile t (3 of t+1 may stay in flight), then barrier
        if (t < 11) asm volatile("s_waitcnt vmcnt(3)" ::: "memory");
        else        asm volatile("s_waitcnt vmcnt(0)" ::: "memory");
        __builtin_amdgcn_s_barrier();
        if (t < 10) { STAGE(t + 2, (t + 2) % 3) }
        const int cur = t % 3;
        bf16x8 af[4], bfm[4];
        #pragma unroll
        for (int rt = 0; rt < 4; ++rt)
            af[rt] = *reinterpret_cast<const bf16x8*>(&As[cur][(wm * 4 + rt) * 512 + lane * 8]);
        #pragma unroll
        for (int ct = 0; ct < 4; ++ct)
            bfm[ct] = *reinterpret_cast<const bf16x8*>(&Bs[cur][(wn * 4 + ct) * 512 + lane * 8]);
        #pragma unroll
        for (int rt = 0; rt < 4; ++rt)
            #pragma unroll
            for (int ct = 0; ct < 4; ++ct)
                acc[rt][ct] = __builtin_amdgcn_mfma_f32_16x16x32_bf16(af[rt], bfm[ct], acc[rt][ct], 0, 0, 0);
        // ensure this tile's ds_reads are complete before next step's stage overwrites
        asm volatile("s_waitcnt lgkmcnt(0)" ::: "memory");
    }
    #undef STAGE

    // epilogue: bias, scale(Q), scatter to qws/kws/vws layouts
    const int lw = mb * 4 + wm;                 // each wave's 64 rows = one window
    const float scale = 0.17677669529663687f;   // 32^-0.5
    const ushort* bias_all = wb + 589824 + wsel * 384;
    #pragma unroll
    for (int ct = 0; ct < 4; ++ct) {
        const int jl = ntm * 128 + wn * 64 + ct * 16 + col16;
        const int head = jl >> 5, hd = jl & 31;
        const float bj = bf2f_us(bias_all[jl]);
        #pragma unroll
        for (int rt = 0; rt < 4; ++rt) {
            if (wsel == 2) {
                ushort4 pk;
                pk.x = f2us(acc[rt][ct][0] + bj);
                pk.y = f2us(acc[rt][ct][1] + bj);
                pk.z = f2us(acc[rt][ct][2] + bj);
                pk.w = f2us(acc[rt][ct][3] + bj);
                *reinterpret_cast<ushort4*>(
                    vws + ((size_t)(lw * NH_ + head) * 32 + hd) * 64 + rt * 16 + quad * 4) = pk;
            } else {
                #pragma unroll
                for (int r = 0; r < 4; ++r) {
                    const int token = rt * 16 + quad * 4 + r;
                    const float v = acc[rt][ct][r] + bj;
                    if (wsel == 0)
                        qws[((size_t)(lw * NH_ + head) * 64 + token) * 32 + hd] = f2us(v * scale);
                    else
                        kws[((size_t)(lw * NH_ + head) * 64 + token) * 32 + hd] = f2us(v);
                }
            }
        }
    }
}

// ---------------- windowed attention: 4 heads (4 waves) per block ----------------
// Output written directly in P1 256-row M-tile layout (head h's 32 dims == K-step h).
__global__ __launch_bounds__(256) void attn_kernel(
    const __hip_bfloat16* __restrict__ qws, const __hip_bfloat16* __restrict__ kws,
    const __hip_bfloat16* __restrict__ vws, const float* __restrict__ biasv,
    ushort* __restrict__ attnout, int wbase)
{
    __shared__ __align__(16) ushort Pbuf[4][64 * 72];
    const int bid = blockIdx.x;
    const int lw = bid / 3, hg = bid - lw * 3;
    const int tid = threadIdx.x, wvi = tid >> 6, lane = tid & 63;
    const int h = hg * 4 + wvi;
    const int w = wbase + lw;
    const int col16 = lane & 15, quad = lane >> 4;
    const ushort* qp = reinterpret_cast<const ushort*>(qws) + ((size_t)lw * NH_ + h) * 64 * 32;
    const ushort* kp = reinterpret_cast<const ushort*>(kws) + ((size_t)lw * NH_ + h) * 64 * 32;
    const ushort* vp = reinterpret_cast<const ushort*>(vws) + ((size_t)lw * NH_ + h) * 32 * 64;

    bf16x8 aq[4], bk4[4];
    #pragma unroll
    for (int t = 0; t < 4; ++t) {
        aq[t]  = *reinterpret_cast<const bf16x8*>(qp + (t * 16 + col16) * 32 + quad * 8);
        bk4[t] = *reinterpret_cast<const bf16x8*>(kp + (t * 16 + col16) * 32 + quad * 8);
    }
    f32x4 S[4][4];
    #pragma unroll
    for (int rt = 0; rt < 4; ++rt) {
        #pragma unroll
        for (int ct = 0; ct < 4; ++ct) {
            f32x4 z = {0.f,0.f,0.f,0.f};
            S[rt][ct] = __builtin_amdgcn_mfma_f32_16x16x32_bf16(aq[rt], bk4[ct], z, 0, 0, 0);
        }
    }

    const int widx = w & 63, wr = widx >> 3, wc = widx & 7;
    const int v = ((wr == 7) ? 2 : 0) + ((wc == 7) ? 1 : 0);
    const float4* bp = reinterpret_cast<const float4*>(biasv) +
                       ((size_t)(v * NH_ + h) * 16) * 64 + lane;
    #pragma unroll
    for (int rt = 0; rt < 4; ++rt) {
        #pragma unroll
        for (int ct = 0; ct < 4; ++ct) {
            const float4 bb = bp[(rt * 4 + ct) * 64];
            S[rt][ct][0] += bb.x; S[rt][ct][1] += bb.y;
            S[rt][ct][2] += bb.z; S[rt][ct][3] += bb.w;
        }
    }

    ushort* pb_w = &Pbuf[wvi][0];
    #pragma unroll
    for (int rt = 0; rt < 4; ++rt) {
        float rm[4], rs[4];
        #pragma unroll
        for (int r = 0; r < 4; ++r)
            rm[r] = fmaxf(fmaxf(S[rt][0][r], S[rt][1][r]), fmaxf(S[rt][2][r], S[rt][3][r]));
        #pragma unroll
        for (int d = 1; d <= 8; d <<= 1) {
            #pragma unroll
            for (int r = 0; r < 4; ++r) rm[r] = fmaxf(rm[r], __shfl_xor(rm[r], d, 64));
        }
        #pragma unroll
        for (int r = 0; r < 4; ++r) rs[r] = 0.f;
        #pragma unroll
        for (int ct = 0; ct < 4; ++ct) {
            #pragma unroll
            for (int r = 0; r < 4; ++r) {
                float p = __expf(S[rt][ct][r] - rm[r]);
                S[rt][ct][r] = p;
                rs[r] += p;
            }
        }
        #pragma unroll
        for (int d = 1; d <= 8; d <<= 1) {
            #pragma unroll
            for (int r = 0; r < 4; ++r) rs[r] += __shfl_xor(rs[r], d, 64);
        }
        #pragma unroll
        for (int ct = 0; ct < 4; ++ct) {
            #pragma unroll
            for (int r = 0; r < 4; ++r) {
                const float inv = 1.0f / rs[r];
                pb_w[(rt * 16 + quad * 4 + r) * 72 + ct * 16 + col16] =
                    f2us(S[rt][ct][r] * inv);
            }
        }
    }
    // Pbuf is per-wave: no barrier needed

    f32x4 O[4][2];
    #pragma unroll
    for (int rt = 0; rt < 4; ++rt) {
        f32x4 z = {0.f,0.f,0.f,0.f};
        O[rt][0] = z; O[rt][1] = z;
    }
    #pragma unroll
    for (int ks = 0; ks < 2; ++ks) {
        bf16x8 bv0 = *reinterpret_cast<const bf16x8*>(vp + (col16)*64 + ks * 32 + quad * 8);
        bf16x8 bv1 = *reinterpret_cast<const bf16x8*>(vp + (16 + col16) * 64 + ks * 32 + quad * 8);
        #pragma unroll
        for (int rt = 0; rt < 4; ++rt) {
            bf16x8 ap = *reinterpret_cast<const bf16x8*>(pb_w + (rt * 16 + col16) * 72 + ks * 32 + quad * 8);
            O[rt][0] = __builtin_amdgcn_mfma_f32_16x16x32_bf16(ap, bv0, O[rt][0], 0, 0, 0);
            O[rt][1] = __builtin_amdgcn_mfma_f32_16x16x32_bf16(ap, bv1, O[rt][1], 0, 0, 0);
        }
    }
    // store O in P1 256-row tile layout: tile mb=lw>>2, step t=h, rb=(lw&3)*4+rt
    ushort* op = attnout + (size_t)(lw >> 2) * 98304 + (size_t)h * 8192 + (lw & 3) * 2048;
    const int elo = col16 & 7;
    #pragma unroll
    for (int rt = 0; rt < 4; ++rt) {
        #pragma unroll
        for (int c2 = 0; c2 < 2; ++c2) {
            const int kch = c2 * 2 + (col16 >> 3);
            #pragma unroll
            for (int r = 0; r < 4; ++r) {
                op[rt * 512 + kch * 128 + (quad * 4 + r) * 8 + elo] = f2us(O[rt][c2][r]);
            }
        }
    }
}

// ---------------- output projection: 256x128 tile, 8 waves, 3-deep pipeline --------------
__global__ __launch_bounds__(512, 4) void proj_gemm(
    const ushort* __restrict__ attnin, const ushort* __restrict__ wb,
    float* __restrict__ out, int wbase, int nmb)
{
    __shared__ __align__(16) ushort As[3][8192];
    __shared__ __align__(16) ushort Bs[3][4096];
    const int nwg = nmb * 3;
    const int orig = blockIdx.x;
    const int wgid = (orig & 7) * (nwg >> 3) + (orig >> 3);
    const int mb = wgid / 3, nt = wgid - mb * 3;
    const int tid = threadIdx.x, lane = tid & 63, wv = tid >> 6;
    const int col16 = lane & 15, quad = lane >> 4;
    const int wm = wv >> 1, wn = wv & 1;

    const ushort* asrc = attnin + (size_t)mb * 98304 + lane * 8;
    const ushort* bsrc = wb + (size_t)(9 + nt) * 49152 + lane * 8;

    f32x4 acc[4][4];
    #pragma unroll
    for (int i2 = 0; i2 < 4; ++i2)
        #pragma unroll
        for (int j2 = 0; j2 < 4; ++j2)
            acc[i2][j2] = (f32x4){0.f, 0.f, 0.f, 0.f};

    #define STAGE(T, BUF)                                                          \
        gload_lds16(asrc + (size_t)(T)*8192 + (2*wv)*512,   &As[BUF][(2*wv)*512]); \
        gload_lds16(asrc + (size_t)(T)*8192 + (2*wv+1)*512, &As[BUF][(2*wv+1)*512]);\
        gload_lds16(bsrc + (size_t)(T)*4096 + wv*512,       &Bs[BUF][wv*512]);

    STAGE(0, 0)
    STAGE(1, 1)

    #pragma unroll
    for (int t = 0; t < 12; ++t) {
        if (t < 11) asm volatile("s_waitcnt vmcnt(3)" ::: "memory");
        else        asm volatile("s_waitcnt vmcnt(0)" ::: "memory");
        __builtin_amdgcn_s_barrier();
        if (t < 10) { STAGE(t + 2, (t + 2) % 3) }
        const int cur = t % 3;
        bf16x8 af[4], bfm[4];
        #pragma unroll
        for (int rt = 0; rt < 4; ++rt)
            af[rt] = *reinterpret_cast<const bf16x8*>(&As[cur][(wm * 4 + rt) * 512 + lane * 8]);
        #pragma unroll
        for (int ct = 0; ct < 4; ++ct)
            bfm[ct] = *reinterpret_cast<const bf16x8*>(&Bs[cur][(wn * 4 + ct) * 512 + lane * 8]);
        #pragma unroll
        for (int rt = 0; rt < 4; ++rt)
            #pragma unroll
            for (int ct = 0; ct < 4; ++ct)
                acc[rt][ct] = __builtin_amdgcn_mfma_f32_16x16x32_bf16(af[rt], bfm[ct], acc[rt][ct], 0, 0, 0);
        asm volatile("s_waitcnt lgkmcnt(0)" ::: "memory");
    }
    #undef STAGE

    const int lw = mb * 4 + wm;
    const int wglob = wbase + lw;
    const int b = wglob >> 6, widx = wglob & 63, wr = widx >> 3, wc = widx & 7;
    const ushort* boc = wb + 589824 + 3 * 384;
    #pragma unroll
    for (int ct = 0; ct < 4; ++ct) {
        const int j = nt * 128 + wn * 64 + ct * 16 + col16;
        const float bj = bf2f_us(boc[j]);
        #pragma unroll
        for (int rt = 0; rt < 4; ++rt) {
            #pragma unroll
            for (int r = 0; r < 4; ++r) {
                const int token = rt * 16 + quad * 4 + r;
                const int orr = (wr * 8 + (token >> 3) + 4) & 63;
                const int occ = (wc * 8 + (token & 7) + 4) & 63;
                out[(((size_t)b * 64 + orr) * 64 + occ) * DIM_ + j] = acc[rt][ct][r] + bj;
            }
        }
    }
}

extern "C" void kernel_launch(void* const* d_in, const int* in_sizes, int n_in,
                              void* d_out, int out_size, void* d_ws, size_t ws_size,
                              hipStream_t stream) {
    const float* x = (const float*)d_in[0];
    float* out = (float*)d_out;
    char* ws = (char*)d_ws;

    // ws layout (bytes):
    //   0        : ushort[594060] bf16 weights(P1 tiles)/biases/table (1,188,120 B)
    //   1188352  : float biasv  (786,432 B) pre-masked C-fragment bias
    //   1974784  : chunk buffers xc(=att)|qws|kws|vws (each WCHUNK*49152 B)
    ushort* wb    = (ushort*)ws;
    float*  biasv = (float*)(ws + 1188352);
    const size_t FIXED = 1974784;

    // wchunk = 512 preferred: per-chunk intermediates ~100 MB stay L3-resident
    // (q/k/v dirty lines re-dirtied each chunk -> HBM write-back mostly avoided).
    int wchunk = 128;
    const int cands[3] = {512, 256, 128};
    for (int i = 0; i < 3; ++i) {
        if (FIXED + (size_t)cands[i] * 4 * 49152 <= ws_size) { wchunk = cands[i]; break; }
    }
    const size_t CQ = (size_t)wchunk * 49152;
    ushort* xcatt = (ushort*)(ws + FIXED);                 // xprep tiles, later attn out
    ushort* qws   = (ushort*)(ws + FIXED + CQ);
    ushort* kws   = (ushort*)(ws + FIXED + 2 * CQ);
    ushort* vws   = (ushort*)(ws + FIXED + 3 * CQ);

    convert_kernel<<<dim3(512), dim3(256), 0, stream>>>(
        (const float*)d_in[1], (const float*)d_in[3], (const float*)d_in[5], (const float*)d_in[7],
        (const float*)d_in[2], (const float*)d_in[4], (const float*)d_in[6], (const float*)d_in[8],
        (const float*)d_in[9], wb);
    bias_kernel<<<dim3(48), dim3(256), 0, stream>>>(wb + 591360, biasv);

    for (int c = 0; c < 2048 / wchunk; ++c) {
        const int wbase = c * wchunk;
        const int nmb = wchunk / 4;   // 256-token (4-window) M-tiles
        xprep_kernel<<<dim3(nmb), dim3(256), 0, stream>>>(x, xcatt, wbase, nmb);
        qkv_gemm<<<dim3(nmb * 9), dim3(512), 0, stream>>>(
            xcatt, wb, qws, kws, vws, nmb);
        attn_kernel<<<dim3(wchunk * 3), dim3(256), 0, stream>>>(
            (const __hip_bfloat16*)qws, (const __hip_bfloat16*)kws,
            (const __hip_bfloat16*)vws, biasv, xcatt, wbase);
        proj_gemm<<<dim3(nmb * 3), dim3(512), 0, stream>>>(
            xcatt, wb, out, wbase, nmb);
    }
}